// Round 4
// baseline (30.891 us; speedup 1.0000x reference)
//
#include <hip/hip_runtime.h>
#include <math.h>
#include <stdint.h>

// ---------------------------------------------------------------------------
// VNFrameEstimator, fused single kernel:
//  - per block: NT=4 tiles x 16 batches, double-buffered LDS staging via
//    global_load_lds(16B) with source-swizzled addresses (q ^= (q>>3)&7) so
//    per-lane 24-float chunk reads (6x ds_read_b128) are bank-conflict-free.
//  - normalize + f64 accumulate (bit-identical math to R2/R3).
//  - 16-lane reduction via DPP row_ror rotate-reduce (VALU pipe, no ds-ops).
//  - block tail: 1 thread/batch 3x3 Jacobi eigensolve in f64 (libm-free),
//    sort, sign-fix, cross, write 3x3 frame. No workspace, no 2nd launch.
// ---------------------------------------------------------------------------

#define BLOCK      256
#define TILE_B     16                    // batches per tile
#define TILE_QUADS (TILE_B * 96)         // 1536 quads = 24 KB
#define NT         4                     // tiles per block
#define BPB        (TILE_B * NT)         // 64 batches per block
#define NSTAGE     6                     // 6 x (4 waves x 1 KB) = 24 KB

// quad-index involution within each 64-quad row: XOR bits[2:0] with bits[5:3]
__device__ __forceinline__ uint32_t swz(uint32_t q) { return q ^ ((q >> 3) & 7u); }

// 1/sqrt(x), ~6e-14 rel err (f32 seed + 1 f64 NR). x in f32-normal range.
__device__ __forceinline__ double fast_rsqrt1(double x) {
    double r = (double)__builtin_amdgcn_rsqf((float)x);
    double h = -0.5 * x;
    r = r * fma(h, r * r, 1.5);
    return r;
}
// 1/sqrt(x), ~1e-15 rel err (2 NR steps).
__device__ __forceinline__ double fast_rsqrt2(double x) {
    double r = (double)__builtin_amdgcn_rsqf((float)x);
    double h = -0.5 * x;
    r = r * fma(h, r * r, 1.5);
    r = r * fma(h, r * r, 1.5);
    return r;
}
// 1/x, ~1e-15 rel err (2 NR steps). |x| f32-representable (guarded by caller).
__device__ __forceinline__ double fast_rcp(double x) {
    double r = (double)__builtin_amdgcn_rcpf((float)x);
    r = r * fma(-x, r, 2.0);
    r = r * fma(-x, r, 2.0);
    return r;
}

// f64 rotate within the 16-lane DPP row (pure VALU, no LDS pipe).
// CTRL: ROW_ROR:N = 0x120|N.
template <int CTRL>
__device__ __forceinline__ double ror16_f64(double v) {
    union { double d; int i[2]; } u, r;
    u.d = v;
    r.i[0] = __builtin_amdgcn_mov_dpp(u.i[0], CTRL, 0xF, 0xF, true);
    r.i[1] = __builtin_amdgcn_mov_dpp(u.i[1], CTRL, 0xF, 0xF, true);
    return r.d;
}

// One Jacobi rotation zeroing A[P][Q]; R is the remaining index.
template <int P, int Q, int R>
__device__ __forceinline__ void jrot(double (&A)[3][3], double (&V)[3][3]) {
    double apq = A[P][Q];
    if (fabs(apq) > 1e-18) {
        double theta = (A[Q][Q] - A[P][P]) * 0.5 * fast_rcp(apq);
        double q = fma(theta, theta, 1.0);
        double sq = (q < 1e37) ? q * fast_rsqrt2(q) : fabs(theta); // sqrt(q)
        double t = fast_rcp(fabs(theta) + sq);
        if (theta < 0.0) t = -t;
        double c = fast_rsqrt2(fma(t, t, 1.0));
        double s = t * c;
        double apq_t = t * apq;
        A[P][P] = A[P][P] - apq_t;
        A[Q][Q] = A[Q][Q] + apq_t;
        A[P][Q] = 0.0;
        A[Q][P] = 0.0;
        double apr = A[P][R], aqr = A[Q][R];
        A[P][R] = c * apr - s * aqr; A[R][P] = A[P][R];
        A[Q][R] = s * apr + c * aqr; A[R][Q] = A[Q][R];
#pragma unroll
        for (int i = 0; i < 3; ++i) {
            double vip = V[i][P], viq = V[i][Q];
            V[i][P] = c * vip - s * viq;
            V[i][Q] = s * vip + c * viq;
        }
    }
}

__global__ __launch_bounds__(BLOCK, 3) void vn_fused(
    const float* __restrict__ vf, float* __restrict__ out, int B) {
    __shared__ float  sbuf[2][TILE_QUADS * 4];   // 2 x 24 KB
    __shared__ double sA[BPB][9];                // 4.5 KB

    const int tid  = threadIdx.x;
    const int wave = tid >> 6;
    const int lane = tid & 63;
    const uint32_t lswz = (uint32_t)lane ^ ((uint32_t)lane >> 3);

    const size_t maxQuad = (size_t)B * 96;
    const size_t tile0   = (size_t)blockIdx.x * NT;

    // stage one 24KB tile: linear LDS writes, source-swizzled global reads
    auto stage = [&](int bufi, int t) {
#pragma unroll
        for (int i = 0; i < NSTAGE; ++i) {
            const uint32_t rowQuad = (uint32_t)(i * 4 + wave) * 64;
            size_t gq = (tile0 + (size_t)t) * TILE_QUADS + rowQuad + lswz;
            if (gq >= maxQuad) gq = maxQuad - 1;    // clamp (pad batches)
            const float* gsrc = vf + gq * 4;
            float* ldst = &sbuf[bufi][((size_t)rowQuad + (uint32_t)lane) * 4];
            __builtin_amdgcn_global_load_lds(
                (__attribute__((address_space(1))) void*)(void*)const_cast<float*>(gsrc),
                (__attribute__((address_space(3))) void*)(void*)ldst,
                16, 0, 0);
        }
    };

    stage(0, 0);
    __syncthreads();   // vmcnt(0) drained before barrier

    const int g   = lane >> 4;
    const int sub = lane & 15;
    const int slotInTile = wave * 4 + g;           // 0..15

    for (int t = 0; t < NT; ++t) {
        if (t + 1 < NT) stage((t + 1) & 1, t + 1);  // prefetch under compute
        const float* buf = sbuf[t & 1];

        const uint32_t baseQuad = (uint32_t)slotInTile * 96 + (uint32_t)sub * 6;
        float f[24];
#pragma unroll
        for (int j = 0; j < 6; ++j) {
            const uint32_t pq = swz(baseQuad + (uint32_t)j);
            const float4 q = *reinterpret_cast<const float4*>(&buf[pq * 4]);
            f[4 * j + 0] = q.x; f[4 * j + 1] = q.y;
            f[4 * j + 2] = q.z; f[4 * j + 3] = q.w;
        }

        double m[9];
#pragma unroll
        for (int k = 0; k < 9; ++k) m[k] = 0.0;

#pragma unroll
        for (int k = 0; k < 8; ++k) {
            float fx = f[3 * k + 0];
            float fy = f[3 * k + 1];
            float fz = f[3 * k + 2];
            float n2f = fmaf(fx, fx, fmaf(fy, fy, fz * fz)); // f32 norm (matches ref)
            double n2 = (double)n2f;
            double inv = (n2 > 1e-24) ? fast_rsqrt1(n2) : 1e12;
            double x = (double)fx * inv;
            double y = (double)fy * inv;
            double z = (double)fz * inv;
            m[0] = fma(x, x, m[0]);
            m[1] = fma(x, y, m[1]);
            m[2] = fma(x, z, m[2]);
            m[3] = fma(y, y, m[3]);
            m[4] = fma(y, z, m[4]);
            m[5] = fma(z, z, m[5]);
            m[6] += x; m[7] += y; m[8] += z;
        }

        // 16-lane rotate-reduce on the VALU pipe (DPP row_ror 1,2,4,8)
#pragma unroll
        for (int k = 0; k < 9; ++k) m[k] += ror16_f64<0x121>(m[k]);
#pragma unroll
        for (int k = 0; k < 9; ++k) m[k] += ror16_f64<0x122>(m[k]);
#pragma unroll
        for (int k = 0; k < 9; ++k) m[k] += ror16_f64<0x124>(m[k]);
#pragma unroll
        for (int k = 0; k < 9; ++k) m[k] += ror16_f64<0x128>(m[k]);

        if (sub == 0) {
            const int slot = t * TILE_B + slotInTile;
#pragma unroll
            for (int k = 0; k < 9; ++k) sA[slot][k] = m[k];
        }
        __syncthreads();  // tile t fully consumed; tile t+1 loads landed
    }

    // ---- fused tail: 1 thread per batch, 3x3 Jacobi eigensolve ----
    if (tid < BPB) {
        const int b = blockIdx.x * BPB + tid;
        if (b < B) {
            double m[9];
#pragma unroll
            for (int k = 0; k < 9; ++k) m[k] = sA[tid][k];

            double A[3][3], V[3][3];
            A[0][0] = m[0] + (double)1e-05f;
            A[0][1] = m[1]; A[1][0] = m[1];
            A[0][2] = m[2]; A[2][0] = m[2];
            A[1][1] = m[3] + (double)2e-05f;
            A[1][2] = m[4]; A[2][1] = m[4];
            A[2][2] = m[5] + (double)3e-05f;
#pragma unroll
            for (int i = 0; i < 3; ++i)
#pragma unroll
                for (int j = 0; j < 3; ++j) V[i][j] = (i == j) ? 1.0 : 0.0;

#pragma unroll
            for (int sweep = 0; sweep < 6; ++sweep) {
                jrot<0, 1, 2>(A, V);
                jrot<0, 2, 1>(A, V);
                jrot<1, 2, 0>(A, V);
            }

            double e0 = A[0][0], e1 = A[1][1], e2 = A[2][2];
            double c0x = V[0][0], c0y = V[1][0], c0z = V[2][0];
            double c1x = V[0][1], c1y = V[1][1], c1z = V[2][1];
            double c2x = V[0][2], c2y = V[1][2], c2z = V[2][2];

#define CSWAP(ea, eb, ax, ay, az, bx, by, bz)                         \
            if (ea > eb) {                                            \
                double t_;                                            \
                t_ = ea; ea = eb; eb = t_;                            \
                t_ = ax; ax = bx; bx = t_;                            \
                t_ = ay; ay = by; by = t_;                            \
                t_ = az; az = bz; bz = t_;                            \
            }
            CSWAP(e0, e1, c0x, c0y, c0z, c1x, c1y, c1z)
            CSWAP(e1, e2, c1x, c1y, c1z, c2x, c2y, c2z)
            CSWAP(e0, e1, c0x, c0y, c0z, c1x, c1y, c1z)
#undef CSWAP

            double s0 = m[6], s1 = m[7], s2 = m[8];
            double d1 = s0 * c0x + s1 * c0y + s2 * c0z;
            double f1 = (d1 < 0.0) ? -1.0 : 1.0;
            c0x *= f1; c0y *= f1; c0z *= f1;
            double d2 = s0 * c1x + s1 * c1y + s2 * c1z;
            double f2 = (d2 < 0.0) ? -1.0 : 1.0;
            c1x *= f2; c1y *= f2; c1z *= f2;

            double v3x = c0y * c1z - c0z * c1y;
            double v3y = c0z * c1x - c0x * c1z;
            double v3z = c0x * c1y - c0y * c1x;

            float* o = out + (size_t)b * 9;
            o[0] = (float)c0x; o[1] = (float)c1x; o[2] = (float)v3x;
            o[3] = (float)c0y; o[4] = (float)c1y; o[5] = (float)v3y;
            o[6] = (float)c0z; o[7] = (float)c1z; o[8] = (float)v3z;
        }
    }
}

extern "C" void kernel_launch(void* const* d_in, const int* in_sizes, int n_in,
                              void* d_out, int out_size, void* d_ws, size_t ws_size,
                              hipStream_t stream) {
    const float* vf = (const float*)d_in[0];
    float* out = (float*)d_out;
    const int B = in_sizes[0] / 384;   // 128 vectors * 3 components
    const int grid = (B + BPB - 1) / BPB;
    vn_fused<<<dim3(grid), dim3(BLOCK), 0, stream>>>(vf, out, B);
}

// Round 5
// 25.664 us; speedup vs baseline: 1.2037x; 1.2037x over previous
//
#include <hip/hip_runtime.h>
#include <math.h>
#include <stdint.h>

// ---------------------------------------------------------------------------
// VNFrameEstimator, fused single kernel (R2 structure + f32 phase 1):
//  - 16 lanes/batch, direct float4 global loads (96B lane stride; dense
//    stream overall, L1 catches the overlap).
//  - normalize + moment-accumulate fully in f32 (comparison is at bf16
//    granularity; f32 moment error ~1e-5 << 2e-2 threshold).
//  - 16-lane reduce via f32 DPP row_ror rotate-reduce (1 v_mov_dpp + 1 add).
//  - fused tail: 1 thread/batch f64 3x3 Jacobi (libm-free), sort, sign-fix,
//    cross, write 3x3 frame.
// ---------------------------------------------------------------------------

#define WAVES_PER_BLOCK 4
#define BLOCK (WAVES_PER_BLOCK * 64)
#define ITERS 2
#define BATCHES_PER_WAVE (4 * ITERS)                 // 8
#define BPB (WAVES_PER_BLOCK * BATCHES_PER_WAVE)     // 32 batches per block

// f32 rotate within the 16-lane DPP row (pure VALU). CTRL: ROW_ROR:N = 0x120|N.
template <int CTRL>
__device__ __forceinline__ float ror16_f32(float v) {
    union { float f; int i; } u, r;
    u.f = v;
    r.i = __builtin_amdgcn_mov_dpp(u.i, CTRL, 0xF, 0xF, true);
    return r.f;
}

// 1/sqrt(x), ~1e-15 rel err (f32 seed + 2 f64 NR steps).
__device__ __forceinline__ double fast_rsqrt2(double x) {
    double r = (double)__builtin_amdgcn_rsqf((float)x);
    double h = -0.5 * x;
    r = r * fma(h, r * r, 1.5);
    r = r * fma(h, r * r, 1.5);
    return r;
}
// 1/x, ~1e-15 rel err (2 NR steps). |x| f32-representable (guarded by caller).
__device__ __forceinline__ double fast_rcp(double x) {
    double r = (double)__builtin_amdgcn_rcpf((float)x);
    r = r * fma(-x, r, 2.0);
    r = r * fma(-x, r, 2.0);
    return r;
}

// One Jacobi rotation zeroing A[P][Q]; R is the remaining index.
template <int P, int Q, int R>
__device__ __forceinline__ void jrot(double (&A)[3][3], double (&V)[3][3]) {
    double apq = A[P][Q];
    if (fabs(apq) > 1e-18) {
        double theta = (A[Q][Q] - A[P][P]) * 0.5 * fast_rcp(apq);
        double q = fma(theta, theta, 1.0);
        double sq = (q < 1e37) ? q * fast_rsqrt2(q) : fabs(theta); // sqrt(q)
        double t = fast_rcp(fabs(theta) + sq);
        if (theta < 0.0) t = -t;
        double c = fast_rsqrt2(fma(t, t, 1.0));
        double s = t * c;
        double apq_t = t * apq;
        A[P][P] = A[P][P] - apq_t;
        A[Q][Q] = A[Q][Q] + apq_t;
        A[P][Q] = 0.0;
        A[Q][P] = 0.0;
        double apr = A[P][R], aqr = A[Q][R];
        A[P][R] = c * apr - s * aqr; A[R][P] = A[P][R];
        A[Q][R] = s * apr + c * aqr; A[R][Q] = A[Q][R];
#pragma unroll
        for (int i = 0; i < 3; ++i) {
            double vip = V[i][P], viq = V[i][Q];
            V[i][P] = c * vip - s * viq;
            V[i][Q] = s * vip + c * viq;
        }
    }
}

__global__ __launch_bounds__(BLOCK) void vn_fused(
    const float* __restrict__ vf, float* __restrict__ out, int B) {
    __shared__ float sA[BPB][9];

    const int tid  = threadIdx.x;
    const int wave = tid >> 6;
    const int lane = tid & 63;
    const int g    = lane >> 4;   // which of 4 batches this iter
    const int sub  = lane & 15;   // lane within 16-group

    const int blockBase = blockIdx.x * BPB;

#pragma unroll
    for (int it = 0; it < ITERS; ++it) {
        const int bslot = wave * BATCHES_PER_WAVE + it * 4 + g;
        const int b = blockBase + bslot;
        if (b < B) {
            // 16 lanes x 24 floats = 384 floats = one batch (128 vectors)
            const float4* p4 =
                reinterpret_cast<const float4*>(vf + (size_t)b * 384 + sub * 24);
            float f[24];
#pragma unroll
            for (int i = 0; i < 6; ++i) {
                float4 q = p4[i];
                f[4 * i + 0] = q.x; f[4 * i + 1] = q.y;
                f[4 * i + 2] = q.z; f[4 * i + 3] = q.w;
            }

            float m[9];
#pragma unroll
            for (int k = 0; k < 9; ++k) m[k] = 0.0f;

#pragma unroll
            for (int k = 0; k < 8; ++k) {
                float fx = f[3 * k + 0];
                float fy = f[3 * k + 1];
                float fz = f[3 * k + 2];
                float n2 = fmaf(fx, fx, fmaf(fy, fy, fz * fz));
                // inv = 1/max(sqrt(n2),1e-12): rsq seed + 1 f32 NR (~1 ulp)
                float r = __builtin_amdgcn_rsqf(n2);
                r = r * fmaf(-0.5f * n2, r * r, 1.5f);
                float inv = (n2 > 1e-24f) ? r : 1e12f;
                float x = fx * inv;
                float y = fy * inv;
                float z = fz * inv;
                m[0] = fmaf(x, x, m[0]);
                m[1] = fmaf(x, y, m[1]);
                m[2] = fmaf(x, z, m[2]);
                m[3] = fmaf(y, y, m[3]);
                m[4] = fmaf(y, z, m[4]);
                m[5] = fmaf(z, z, m[5]);
                m[6] += x; m[7] += y; m[8] += z;
            }

            // 16-lane rotate-reduce on the VALU pipe (DPP row_ror 1,2,4,8)
#pragma unroll
            for (int k = 0; k < 9; ++k) m[k] += ror16_f32<0x121>(m[k]);
#pragma unroll
            for (int k = 0; k < 9; ++k) m[k] += ror16_f32<0x122>(m[k]);
#pragma unroll
            for (int k = 0; k < 9; ++k) m[k] += ror16_f32<0x124>(m[k]);
#pragma unroll
            for (int k = 0; k < 9; ++k) m[k] += ror16_f32<0x128>(m[k]);

            if (sub == 0) {
#pragma unroll
                for (int k = 0; k < 9; ++k) sA[bslot][k] = m[k];
            }
        }
    }

    __syncthreads();

    // ---- fused tail: 1 thread per batch, f64 3x3 Jacobi eigensolve ----
    if (tid < BPB) {
        const int b = blockBase + tid;
        if (b < B) {
            double m[9];
#pragma unroll
            for (int k = 0; k < 9; ++k) m[k] = (double)sA[tid][k];

            double A[3][3], V[3][3];
            A[0][0] = m[0] + (double)1e-05f;
            A[0][1] = m[1]; A[1][0] = m[1];
            A[0][2] = m[2]; A[2][0] = m[2];
            A[1][1] = m[3] + (double)2e-05f;
            A[1][2] = m[4]; A[2][1] = m[4];
            A[2][2] = m[5] + (double)3e-05f;
#pragma unroll
            for (int i = 0; i < 3; ++i)
#pragma unroll
                for (int j = 0; j < 3; ++j) V[i][j] = (i == j) ? 1.0 : 0.0;

#pragma unroll
            for (int sweep = 0; sweep < 6; ++sweep) {
                jrot<0, 1, 2>(A, V);
                jrot<0, 2, 1>(A, V);
                jrot<1, 2, 0>(A, V);
            }

            double e0 = A[0][0], e1 = A[1][1], e2 = A[2][2];
            double c0x = V[0][0], c0y = V[1][0], c0z = V[2][0];
            double c1x = V[0][1], c1y = V[1][1], c1z = V[2][1];
            double c2x = V[0][2], c2y = V[1][2], c2z = V[2][2];

#define CSWAP(ea, eb, ax, ay, az, bx, by, bz)                         \
            if (ea > eb) {                                            \
                double t_;                                            \
                t_ = ea; ea = eb; eb = t_;                            \
                t_ = ax; ax = bx; bx = t_;                            \
                t_ = ay; ay = by; by = t_;                            \
                t_ = az; az = bz; bz = t_;                            \
            }
            CSWAP(e0, e1, c0x, c0y, c0z, c1x, c1y, c1z)
            CSWAP(e1, e2, c1x, c1y, c1z, c2x, c2y, c2z)
            CSWAP(e0, e1, c0x, c0y, c0z, c1x, c1y, c1z)
#undef CSWAP

            double s0 = m[6], s1 = m[7], s2 = m[8];
            double d1 = s0 * c0x + s1 * c0y + s2 * c0z;
            double f1 = (d1 < 0.0) ? -1.0 : 1.0;
            c0x *= f1; c0y *= f1; c0z *= f1;
            double d2 = s0 * c1x + s1 * c1y + s2 * c1z;
            double f2 = (d2 < 0.0) ? -1.0 : 1.0;
            c1x *= f2; c1y *= f2; c1z *= f2;

            double v3x = c0y * c1z - c0z * c1y;
            double v3y = c0z * c1x - c0x * c1z;
            double v3z = c0x * c1y - c0y * c1x;

            float* o = out + (size_t)b * 9;
            o[0] = (float)c0x; o[1] = (float)c1x; o[2] = (float)v3x;
            o[3] = (float)c0y; o[4] = (float)c1y; o[5] = (float)v3y;
            o[6] = (float)c0z; o[7] = (float)c1z; o[8] = (float)v3z;
        }
    }
}

extern "C" void kernel_launch(void* const* d_in, const int* in_sizes, int n_in,
                              void* d_out, int out_size, void* d_ws, size_t ws_size,
                              hipStream_t stream) {
    const float* vf = (const float*)d_in[0];
    float* out = (float*)d_out;
    const int B = in_sizes[0] / 384;   // 128 vectors * 3 components
    const int grid = (B + BPB - 1) / BPB;
    vn_fused<<<dim3(grid), dim3(BLOCK), 0, stream>>>(vf, out, B);
}